// Round 11
// baseline (218.810 us; speedup 1.0000x reference)
//
#include <hip/hip_runtime.h>

typedef __attribute__((ext_vector_type(8))) short  short8;
typedef __attribute__((ext_vector_type(4))) float  floatx4;
typedef __attribute__((ext_vector_type(4))) int    intx4;

constexpr int DIN = 100;
constexpr int H   = 64;
constexpr int G   = 10;
constexpr int NH  = 5;
constexpr int MWG = 128;                 // rows per block (4 waves x 32 rows)
constexpr int PBP = 20;                  // pbuf pitch (floats): 16 payload + 4 pad

// fragment counts in ws: dW0 (K=128 padded) 16; dW1 8; dbW 2; W0 5h*8=40
constexpr int NF_DW0 = 16, NF_DW1 = 8, NF_DBW = 2;
constexpr int NF_LIN = NF_DW0 + NF_DW1 + NF_DBW;     // 26
constexpr int NF_TOT = NF_LIN + 40;                  // 66 (ALL staged in LDS)

__device__ __forceinline__ unsigned short f2bf_rne(float f) {
    union { float f; unsigned u; } v{f};
    unsigned r = v.u + 0x7FFF + ((v.u >> 16) & 1);   // RNE
    return (unsigned short)(r >> 16);
}

// round-half-up pack of 8 floats -> short8 (bf16)
__device__ __forceinline__ short8 pack8(const float* f) {
    intx4 p;
    #pragma unroll
    for (int j = 0; j < 4; ++j) {
        unsigned a = __float_as_uint(f[2 * j])     + 0x8000u;
        unsigned b = __float_as_uint(f[2 * j + 1]) + 0x8000u;
        p[j] = (int)((b & 0xFFFF0000u) | (a >> 16));
    }
    union { intx4 i; short8 s; } u; u.i = p;
    return u.s;
}

// full barrier incl. vmcnt drain (used once: staging+x -> layer1)
__device__ __forceinline__ void bar_vm() {
    asm volatile("s_waitcnt vmcnt(0) lgkmcnt(0)" ::: "memory");
    __builtin_amdgcn_s_barrier();
    asm volatile("" ::: "memory");
}

// ---- pre-kernel: pack all weights as bf16 MFMA fragments into ws ----
// Layout note: lane holds W[k = (lane>>4)*8 + j][n = lane&15]. This is
// simultaneously the B-fragment of W and the A-fragment of W^T — the main
// kernel uses them as A-operands to compute transposed outputs h^T.
__global__ __launch_bounds__(64) void pack_kernel(
    const float* __restrict__ dW0, const float* __restrict__ dW1,
    const float* __restrict__ dbW, const float* __restrict__ W0,
    unsigned short* __restrict__ ws)
{
    const int f = blockIdx.x;            // fragment id 0..65
    const int lane = threadIdx.x;
    const int q = lane >> 4, cl = lane & 15;
    float v[8];
    if (f < NF_DW0) {                    // dW0: K padded 100->128 with zeros
        int c = f >> 2, g = f & 3;
        #pragma unroll
        for (int j = 0; j < 8; ++j) {
            int k = c * 32 + q * 8 + j, n = g * 16 + cl;
            v[j] = (k < DIN) ? dW0[k * H + n] : 0.0f;
        }
    } else if (f < NF_DW0 + NF_DW1) {    // dW1: K=64
        int r = f - NF_DW0; int c = r >> 2, g = r & 3;
        #pragma unroll
        for (int j = 0; j < 8; ++j) {
            int k = c * 32 + q * 8 + j, n = g * 16 + cl;
            v[j] = dW1[k * H + n];
        }
    } else if (f < NF_LIN) {             // dbW: K=64, N=11 padded to 16
        int c = f - (NF_DW0 + NF_DW1);
        #pragma unroll
        for (int j = 0; j < 8; ++j) {
            int k = c * 32 + q * 8 + j, n = cl;
            v[j] = (n <= G) ? dbW[k * (G + 1) + n] : 0.0f;
        }
    } else {                             // W0: 5 heads, K=64
        int r = f - NF_LIN; int h = r >> 3; r &= 7; int c = r >> 2, g = r & 3;
        #pragma unroll
        for (int j = 0; j < 8; ++j) {
            int k = c * 32 + q * 8 + j, n = g * 16 + cl;
            v[j] = W0[(h * H + k) * H + n];
        }
    }
    short8 s;
    #pragma unroll
    for (int j = 0; j < 8; ++j) s[j] = (short)f2bf_rne(v[j]);
    *(short8*)(ws + (size_t)(f * 64 + lane) * 8) = s;
}

// ---- main kernel (operand-swapped MFMAs: D = W^T @ x^T = h^T) ----
// ALL 66 weight fragments staged in LDS once per block (global_load_lds,
// lane x 16B layout). NO hbuf: layer transitions are in-register lane
// shuffles (thread (q,cl) needs h[c*32+q*8+jj][cl]; holder is lane
// ((q&1)*2+(jj>>2))*16+cl, reg pv[2c+(q>>1)][jj&3] -> 2 shfl + select,
// all reg indices compile-time). NO sort: heads run all 5 buckets
// lockstep from LDS frags, epilogue exec-masked (one pass total).
// Exactly ONE barrier (post-staging vmcnt drain); rest is wave-private.
__global__ __launch_bounds__(256, 2) void drnet_mfma(
    const float* __restrict__ dosage, const float* __restrict__ x,
    const float* __restrict__ db0, const float* __restrict__ db1,
    const float* __restrict__ dbB,
    const float* __restrict__ tw0, const float* __restrict__ b0,
    const float* __restrict__ W1, const float* __restrict__ tw1,
    const float* __restrict__ b1,
    const unsigned short* __restrict__ wsfrag,
    float* __restrict__ outg, float* __restrict__ outq)
{
    __shared__ unsigned short wstage[NF_TOT * 512];  // 67584 B: all fragments
    __shared__ float          pbuf[4][16][PBP];      //  5120 B: softmax scratch

    const int tid  = threadIdx.x;
    const int wave = tid >> 6, lane = tid & 63;
    const int q = lane >> 4, cl = lane & 15;
    const int rowbase = blockIdx.x * MWG + wave * 32;   // this wave's 32 rows

    // frag read from LDS stage (lane i holds bytes [16i,16i+16) of frag f)
    auto ldsfrag = [&](int f) -> short8 {
        return *(const short8*)(wstage + f * 512 + lane * 8);
    };

    // shfl-transpose: from C-layout pv pairs (g=2c, g=2c+1) to the next
    // layer's A/B fragment short8 (verified mapping; rounding after shfl
    // is identical to the old hbuf pack -> bit-identical numerics).
    auto xpose = [&](const floatx4 plo, const floatx4 phi) -> short8 {
        float f[8];
        const int sbase = ((q & 1) * 2) * 16 + cl;
        #pragma unroll
        for (int jj = 0; jj < 8; ++jj) {
            const int srcl = sbase + ((jj >> 2) << 4);
            const float vlo = __shfl(plo[jj & 3], srcl);
            const float vhi = __shfl(phi[jj & 3], srcl);
            f[jj] = (q >> 1) ? vhi : vlo;
        }
        return pack8(f);
    };

    // ======= phase -1a: issue LDS staging of ALL 66 fragments =======
    #pragma unroll
    for (int f0 = 0; f0 < 68; f0 += 4) {             // waves round-robin frags
        const int f = f0 + wave;
        if (f < NF_TOT) {
            __builtin_amdgcn_global_load_lds(
                (const __attribute__((address_space(1))) void*)
                    (wsfrag + (size_t)(f * 64 + lane) * 8),
                (__attribute__((address_space(3))) void*)
                    (wstage + f * 512),
                16, 0, 0);
        }
    }

    // ======= phase -1b: issue this wave's x / dosage global loads =======
    float tden[2];
    #pragma unroll
    for (int mt = 0; mt < 2; ++mt)
        tden[mt] = dosage[rowbase + mt * 16 + cl];
    floatx4 xv[2][7];
    #pragma unroll
    for (int mt = 0; mt < 2; ++mt) {
        const float* xr = x + (size_t)(rowbase + mt * 16 + cl) * DIN;
        #pragma unroll
        for (int cch = 0; cch < 3; ++cch) {
            xv[mt][2 * cch]     = *(const floatx4*)(xr + cch * 32 + q * 8);
            xv[mt][2 * cch + 1] = *(const floatx4*)(xr + cch * 32 + q * 8 + 4);
        }
        xv[mt][6] = (q == 0) ? *(const floatx4*)(xr + 96) : (floatx4)0.0f;
    }

    bar_vm();    // staging + x + dosage complete; wstage visible to all waves

    // ====== layer 1: h1^T = dW0^T @ x^T, both mt merged (8 acc chains) ======
    short8 a2[2][2];                     // h1^T fragments (register-only)
    {
        short8 a1[2][4];
        #pragma unroll
        for (int mt = 0; mt < 2; ++mt)
            #pragma unroll
            for (int cch = 0; cch < 4; ++cch) {
                float f[8];
                if (cch < 3) {
                    #pragma unroll
                    for (int j = 0; j < 4; ++j) {
                        f[j]     = xv[mt][2 * cch][j];
                        f[4 + j] = xv[mt][2 * cch + 1][j];
                    }
                } else {
                    #pragma unroll
                    for (int j = 0; j < 4; ++j) {
                        f[j]     = xv[mt][6][j];
                        f[4 + j] = 0.0f;
                    }
                }
                a1[mt][cch] = pack8(f);
            }
        floatx4 acc[2][4];
        #pragma unroll
        for (int mt = 0; mt < 2; ++mt)
            #pragma unroll
            for (int g = 0; g < 4; ++g) acc[mt][g] = (floatx4)0.0f;
        #pragma unroll
        for (int cch = 0; cch < 4; ++cch)
            #pragma unroll
            for (int g = 0; g < 4; ++g) {
                short8 bf = ldsfrag(cch * 4 + g);        // LDS, shared by both mt
                acc[0][g] = __builtin_amdgcn_mfma_f32_16x16x32_bf16(bf, a1[0][cch], acc[0][g], 0, 0, 0);
                acc[1][g] = __builtin_amdgcn_mfma_f32_16x16x32_bf16(bf, a1[1][cch], acc[1][g], 0, 0, 0);
            }
        #pragma unroll
        for (int mt = 0; mt < 2; ++mt) {
            floatx4 pv[4];
            #pragma unroll
            for (int g = 0; g < 4; ++g) {
                floatx4 bias = *(const floatx4*)(db0 + g * 16 + 4 * q);
                #pragma unroll
                for (int r = 0; r < 4; ++r)
                    pv[g][r] = fmaxf(acc[mt][g][r] + bias[r], 0.0f);
            }
            a2[mt][0] = xpose(pv[0], pv[1]);
            a2[mt][1] = xpose(pv[2], pv[3]);
        }
    }

    // ====== layer 2: h2^T = dW1^T @ h1^T, both mt merged ======
    short8 af[2][2];                     // h2^T fragments (register-only)
    {
        floatx4 acc[2][4];
        #pragma unroll
        for (int mt = 0; mt < 2; ++mt)
            #pragma unroll
            for (int g = 0; g < 4; ++g) acc[mt][g] = (floatx4)0.0f;
        #pragma unroll
        for (int cch = 0; cch < 2; ++cch)
            #pragma unroll
            for (int g = 0; g < 4; ++g) {
                short8 bf = ldsfrag(NF_DW0 + cch * 4 + g);
                acc[0][g] = __builtin_amdgcn_mfma_f32_16x16x32_bf16(bf, a2[0][cch], acc[0][g], 0, 0, 0);
                acc[1][g] = __builtin_amdgcn_mfma_f32_16x16x32_bf16(bf, a2[1][cch], acc[1][g], 0, 0, 0);
            }
        #pragma unroll
        for (int mt = 0; mt < 2; ++mt) {
            floatx4 pv[4];
            #pragma unroll
            for (int g = 0; g < 4; ++g) {
                floatx4 bias = *(const floatx4*)(db1 + g * 16 + 4 * q);
                #pragma unroll
                for (int r = 0; r < 4; ++r)
                    pv[g][r] = fmaxf(acc[mt][g][r] + bias[r], 0.0f);
            }
            af[mt][0] = xpose(pv[0], pv[1]);
            af[mt][1] = xpose(pv[2], pv[3]);
        }
    }

    // ====== density: p^T = softmax(dbW^T @ h2^T + dbB) + interp ======
    // thread holds logits for grid dims 4q+r of batch row cl
    {
        floatx4 accd[2];
        accd[0] = (floatx4)0.0f; accd[1] = (floatx4)0.0f;
        #pragma unroll
        for (int cch = 0; cch < 2; ++cch) {
            short8 bf = ldsfrag(NF_DW0 + NF_DW1 + cch);
            #pragma unroll
            for (int mt = 0; mt < 2; ++mt)
                accd[mt] = __builtin_amdgcn_mfma_f32_16x16x32_bf16(bf, af[mt][cch], accd[mt], 0, 0, 0);
        }
        #pragma unroll
        for (int mt = 0; mt < 2; ++mt) {
            floatx4 ev;
            float sp = 0.0f;
            #pragma unroll
            for (int r = 0; r < 4; ++r) {
                const int gd = 4 * q + r;
                float e = (gd <= G) ? __expf(accd[mt][r] + dbB[gd]) : 0.0f;
                ev[r] = e;
                sp += e;
            }
            float s = sp;
            s += __shfl_xor(s, 16); s += __shfl_xor(s, 32);   // sum over grid dims
            *(floatx4*)(&pbuf[wave][cl][4 * q]) = ev;         // exchange across q
            const float tt = tden[mt];
            const float tB = tt * (float)G;
            const float U  = ceilf(tB);
            const float inter = 1.0f - (U - tB);
            int Ui = (int)U; int Li = Ui - 1; if (Li < 0) Li = 0;
            const float pL = pbuf[wave][cl][Li];
            const float pU = pbuf[wave][cl][Ui];
            if (q == 0)
                outg[rowbase + mt * 16 + cl] = (pL + (pU - pL) * inter) / s;
        }
    }

    // ====== heads: all 5 lockstep from LDS frags; exec-masked epilogue ======
    {
        int bkme[2];
        #pragma unroll
        for (int mt = 0; mt < 2; ++mt)
            bkme[mt] = min(max((int)floorf(tden[mt] * (float)NH), 0), NH - 1);
        float qp[2] = {0.0f, 0.0f};
        #pragma unroll 1
        for (int h = 0; h < NH; ++h) {
            floatx4 acch[2][4];
            #pragma unroll
            for (int mt = 0; mt < 2; ++mt)
                #pragma unroll
                for (int g = 0; g < 4; ++g) acch[mt][g] = (floatx4)0.0f;
            #pragma unroll
            for (int cch = 0; cch < 2; ++cch)
                #pragma unroll
                for (int g = 0; g < 4; ++g) {
                    short8 bf = ldsfrag(NF_LIN + h * 8 + cch * 4 + g);
                    acch[0][g] = __builtin_amdgcn_mfma_f32_16x16x32_bf16(bf, af[0][cch], acch[0][g], 0, 0, 0);
                    acch[1][g] = __builtin_amdgcn_mfma_f32_16x16x32_bf16(bf, af[1][cch], acch[1][g], 0, 0, 0);
                }
            #pragma unroll
            for (int mt = 0; mt < 2; ++mt) {
                if (bkme[mt] == h) {     // exec-masked: total epilogue ~= one pass
                    #pragma unroll
                    for (int g = 0; g < 4; ++g) {
                        const int off = h * H + g * 16 + 4 * q;
                        floatx4 tw0v = *(const floatx4*)(tw0 + off);
                        floatx4 b0v  = *(const floatx4*)(b0  + off);
                        floatx4 w1v  = *(const floatx4*)(W1  + off);
                        #pragma unroll
                        for (int r = 0; r < 4; ++r)
                            qp[mt] += fmaxf(acch[mt][g][r] + tden[mt] * tw0v[r] + b0v[r], 0.0f) * w1v[r];
                    }
                }
            }
        }
        #pragma unroll
        for (int mt = 0; mt < 2; ++mt) {
            float s = qp[mt];
            s += __shfl_xor(s, 16); s += __shfl_xor(s, 32);   // sum over hid
            if (q == 0)
                outq[rowbase + mt * 16 + cl] =
                    s + tden[mt] * tw1[bkme[mt]] + b1[bkme[mt]];
        }
    }
}

extern "C" void kernel_launch(void* const* d_in, const int* in_sizes, int n_in,
                              void* d_out, int out_size, void* d_ws, size_t ws_size,
                              hipStream_t stream) {
    const float* dosage = (const float*)d_in[0];
    const float* x      = (const float*)d_in[1];
    const float* dW0    = (const float*)d_in[2];
    const float* db0    = (const float*)d_in[3];
    const float* dW1    = (const float*)d_in[4];
    const float* db1    = (const float*)d_in[5];
    const float* dbW    = (const float*)d_in[6];
    const float* dbB    = (const float*)d_in[7];
    const float* W0     = (const float*)d_in[8];
    const float* tw0    = (const float*)d_in[9];
    const float* b0     = (const float*)d_in[10];
    const float* W1     = (const float*)d_in[11];
    const float* tw1    = (const float*)d_in[12];
    const float* b1     = (const float*)d_in[13];

    const int Btot = in_sizes[0];
    float* outg = (float*)d_out;
    float* outq = outg + Btot;
    unsigned short* ws = (unsigned short*)d_ws;

    pack_kernel<<<NF_TOT, 64, 0, stream>>>(dW0, dW1, dbW, W0, ws);
    drnet_mfma<<<Btot / MWG, 256, 0, stream>>>(dosage, x, db0, db1, dbB,
                                               tw0, b0, W1, tw1, b1,
                                               ws, outg, outq);
}